// Round 1
// 652.494 us; speedup vs baseline: 1.4886x; 1.4886x over previous
//
#include <hip/hip_runtime.h>
#include <hip/hip_bf16.h>
#include <math.h>

#define B_IMG 16
#define HH 112
#define WW_ 112
#define CC 128
#define LL (HH*WW_)            // 12544
#define BWIN 4096
#define NTOK 49
#define NROWS (BWIN*NTOK)      // 200704
#define HD 32
#define SCALE 0.1767766952966369f   // 1/sqrt(32)
#define SHIFT_ 3

typedef short bf16x8 __attribute__((ext_vector_type(8)));
typedef float f32x4 __attribute__((ext_vector_type(4)));
typedef unsigned short ushort_t;

// ---------------------------------------------------------------- helpers
__device__ __forceinline__ float wave_sum(float v) {
#pragma unroll
  for (int off = 32; off >= 1; off >>= 1) v += __shfl_xor(v, off, 64);
  return v;
}

__global__ __launch_bounds__(256) void castw_kernel(const float* __restrict__ w,
                                                    __hip_bfloat16* __restrict__ o, int n) {
  int i = blockIdx.x * 256 + threadIdx.x;
  if (i < n) o[i] = __float2bfloat16(w[i]);
}

// ---------------------------------------------------------------- attention prep tables
// biasPad[h][64][64]: rel-pos bias, 0 in padding. maskPad[pat][64][64]: shift mask,
// -1e30 in padding (kills cols k>=49; rows q>=49 are never stored).
__global__ __launch_bounds__(256) void prep_bias(const float* __restrict__ table,
                                                 float* __restrict__ biasPad) {
  int idx = blockIdx.x * 256 + threadIdx.x;      // 4*64*64 = 16384
  int h = idx >> 12, q = (idx >> 6) & 63, k = idx & 63;
  float v = 0.f;
  if (q < NTOK && k < NTOK) {
    int yi = q / 7, xi = q % 7, yj = k / 7, xj = k % 7;
    v = table[((yi - yj + 6) * 13 + (xi - xj + 6)) * 4 + h];
  }
  biasPad[idx] = v;
}

__global__ __launch_bounds__(256) void prep_mask(const float* __restrict__ mask,
                                                 float* __restrict__ maskPad) {
  int idx = blockIdx.x * 256 + threadIdx.x;      // 256*64*64 = 1048576
  int pat = idx >> 12, q = (idx >> 6) & 63, k = idx & 63;
  float v = -1e30f;
  if (q < NTOK && k < NTOK) v = mask[pat * (NTOK * NTOK) + q * NTOK + k];
  maskPad[idx] = v;
}

// ---------------------------------------------------------------- LayerNorm (fp32 in, bf16 out)
template<bool GATHER>
__global__ __launch_bounds__(256) void ln_kernel(
    const float* __restrict__ X, const float* __restrict__ g,
    const float* __restrict__ b, __hip_bfloat16* __restrict__ Y)
{
  int wid  = threadIdx.x >> 6;
  int lane = threadIdx.x & 63;
  int r = blockIdx.x * 4 + wid;
  size_t src;
  if (GATHER) {
    int win = r / NTOK, n = r % NTOK;
    int bi = win >> 8, wi = win & 255;
    int wh = wi >> 4, wwi = wi & 15;
    int ii = n / 7, jj = n % 7;
    int hp = wh * 7 + ii, wp = wwi * 7 + jj;
    int sh = (hp + SHIFT_) % HH, sw = (wp + SHIFT_) % WW_;   // roll(-3) gather
    src = ((size_t)bi * LL + (size_t)sh * WW_ + sw) * CC;
  } else {
    src = (size_t)r * CC;
  }
  float v0 = X[src + lane];
  float v1 = X[src + 64 + lane];
  float mean = wave_sum(v0 + v1) * (1.f / CC);
  float d0 = v0 - mean, d1 = v1 - mean;
  float var = wave_sum(d0 * d0 + d1 * d1) * (1.f / CC);
  float rstd = rsqrtf(var + 1e-5f);
  size_t dst = (size_t)r * CC;
  Y[dst + lane]      = __float2bfloat16(d0 * rstd * g[lane]      + b[lane]);
  Y[dst + 64 + lane] = __float2bfloat16(d1 * rstd * g[lane + 64] + b[lane + 64]);
}

// ---------------------------------------------------------------- bf16 MFMA GEMM
// C[m][n] = sum_k A[m][k]*W[n][k] + bias[n]  (+ epilogue). A,W bf16; acc fp32.
// 128x128 tile, 256 thr = 4 waves (2x2), each wave 64x64 via 4x4 of 16x16x32.
enum { EPI_BIAS = 0, EPI_GELU = 1, EPI_RES = 2, EPI_PROJ = 3 };
#define LDSW 136   // 128 + 8 pad: keeps 16B alignment, breaks bank-phase

template<int EPI>
__global__ __launch_bounds__(256, 2) void gemm_bf16(
    const ushort_t* __restrict__ A, const ushort_t* __restrict__ W,
    const float* __restrict__ bias, const float* __restrict__ aux,
    void* __restrict__ outp, int N, int K)
{
  __shared__ ushort_t As[128 * LDSW];
  __shared__ ushort_t Bs[128 * LDSW];
  int t = threadIdx.x;
  int lane = t & 63;
  int quad = lane >> 4;
  int l16  = lane & 15;
  int wr = (t >> 7) * 64;        // wave row offset in tile
  int wc = ((t >> 6) & 1) * 64;  // wave col offset in tile
  int m0 = blockIdx.x * 128, n0 = blockIdx.y * 128;

  f32x4 acc[4][4];
#pragma unroll
  for (int i = 0; i < 4; ++i)
#pragma unroll
    for (int j = 0; j < 4; ++j) acc[i][j] = (f32x4){0.f, 0.f, 0.f, 0.f};

  for (int kb = 0; kb < K; kb += 128) {
    if (kb) __syncthreads();
    // stage 128x128 bf16 panels of A and W
#pragma unroll
    for (int p = 0; p < 8; ++p) {
      int lin = p * 256 + t;
      int row = lin >> 4;
      int col = (lin & 15) * 8;
      uint4 av = *(const uint4*)(A + (size_t)(m0 + row) * K + kb + col);
      uint4 bv = *(const uint4*)(W + (size_t)(n0 + row) * K + kb + col);
      *(uint4*)&As[row * LDSW + col] = av;
      *(uint4*)&Bs[row * LDSW + col] = bv;
    }
    __syncthreads();
#pragma unroll
    for (int ks = 0; ks < 4; ++ks) {
      int k0 = ks * 32 + quad * 8;
      bf16x8 af[4], bf[4];
#pragma unroll
      for (int i = 0; i < 4; ++i)
        af[i] = *(const bf16x8*)&As[(wr + i * 16 + l16) * LDSW + k0];
#pragma unroll
      for (int j = 0; j < 4; ++j)
        bf[j] = *(const bf16x8*)&Bs[(wc + j * 16 + l16) * LDSW + k0];
#pragma unroll
      for (int i = 0; i < 4; ++i)
#pragma unroll
        for (int j = 0; j < 4; ++j)
          acc[i][j] = __builtin_amdgcn_mfma_f32_16x16x32_bf16(af[i], bf[j], acc[i][j], 0, 0, 0);
    }
  }

  // epilogue: C/D layout col=lane&15, row=quad*4+reg
#pragma unroll
  for (int i = 0; i < 4; ++i) {
#pragma unroll
    for (int j = 0; j < 4; ++j) {
      int n = n0 + wc + j * 16 + l16;
      float bn = bias[n];
#pragma unroll
      for (int reg = 0; reg < 4; ++reg) {
        int m = m0 + wr + i * 16 + quad * 4 + reg;
        float v = acc[i][j][reg] + bn;
        if (EPI == EPI_BIAS) {
          ((__hip_bfloat16*)outp)[(size_t)m * N + n] = __float2bfloat16(v);
        } else if (EPI == EPI_GELU) {
          v = 0.5f * v * (1.f + erff(v * 0.70710678118654752f));
          ((__hip_bfloat16*)outp)[(size_t)m * N + n] = __float2bfloat16(v);
        } else if (EPI == EPI_RES) {
          // in-place residual (aux aliases outp; same element, same thread)
          ((float*)outp)[(size_t)m * N + n] = v + aux[(size_t)m * N + n];
        } else { // EPI_PROJ: window-reverse + roll(+3,+3) + shortcut, scatter fp32
          int win = m / NTOK, nn = m % NTOK;
          int bi = win >> 8, wi = win & 255;
          int wh = wi >> 4, wwi = wi & 15;
          int ii = nn / 7, jj = nn % 7;
          int hp = wh * 7 + ii, wp = wwi * 7 + jj;
          int oh = (hp + SHIFT_) % HH, ow = (wp + SHIFT_) % WW_;
          size_t idx = ((size_t)bi * LL + (size_t)oh * WW_ + ow) * CC + n;
          ((float*)outp)[idx] = aux[idx] + v;
        }
      }
    }
  }
}

// ---------------------------------------------------------------- MFMA attention
// 1 block = 1 window; 4 waves = 4 heads; tokens padded 49->64.
// Per-wave LDS pool (ushort units): [0,4608)   P (64 x stride72, bf16)
//                                   [0,2560)   Ks (64 x stride40) -- overlaid by P after QK^T
//                                   [4608,6656) Vt (32 x stride64)
#define WLDS 6656

__global__ __launch_bounds__(256) void attn_mfma(
    const ushort_t* __restrict__ qkv, const float* __restrict__ maskPad,
    const float* __restrict__ biasPad, __hip_bfloat16* __restrict__ O, int win_off)
{
  __shared__ ushort_t lds[4 * WLDS];
  const int win_l = blockIdx.x;
  const int win_g = win_off + win_l;
  const int h    = threadIdx.x >> 6;
  const int lane = threadIdx.x & 63;
  const int quad = lane >> 4;
  const int l16  = lane & 15;
  ushort_t* wb = lds + h * WLDS;     // Ks, later P
  ushort_t* Vt = wb + 4608;

  // ---- stage K (zero-padded rows to 64) and V^T for this head (wave-private)
  {
    const int tok = lane;
    uint4 z = make_uint4(0u, 0u, 0u, 0u);
    uint4 k0 = z, k1 = z, k2 = z, k3 = z;
    union { uint4 v4[4]; ushort_t u[32]; } vv;
    vv.v4[0] = z; vv.v4[1] = z; vv.v4[2] = z; vv.v4[3] = z;
    if (tok < NTOK) {
      const ushort_t* src = qkv + ((size_t)win_l * NTOK + tok) * 384 + h * HD;
      k0 = *(const uint4*)(src + 128); k1 = *(const uint4*)(src + 136);
      k2 = *(const uint4*)(src + 144); k3 = *(const uint4*)(src + 152);
      vv.v4[0] = *(const uint4*)(src + 256); vv.v4[1] = *(const uint4*)(src + 264);
      vv.v4[2] = *(const uint4*)(src + 272); vv.v4[3] = *(const uint4*)(src + 280);
    }
    *(uint4*)&wb[tok * 40 +  0] = k0;
    *(uint4*)&wb[tok * 40 +  8] = k1;
    *(uint4*)&wb[tok * 40 + 16] = k2;
    *(uint4*)&wb[tok * 40 + 24] = k3;
#pragma unroll
    for (int d = 0; d < 32; ++d) Vt[d * 64 + tok] = vv.u[d];
  }

  // ---- Q fragments straight from global (rows >=49 read garbage; those S rows unused)
  bf16x8 qf[4];
  {
    const ushort_t* qb = qkv + (size_t)win_l * NTOK * 384 + h * HD + quad * 8;
#pragma unroll
    for (int i = 0; i < 4; ++i)
      qf[i] = *(const bf16x8*)(qb + (size_t)(i * 16 + l16) * 384);
  }

  // ---- S = Q K^T  (16 MFMAs). A rows from qf(l16), B cols from kf(l16).
  f32x4 S[4][4];
#pragma unroll
  for (int i = 0; i < 4; ++i)
#pragma unroll
    for (int j = 0; j < 4; ++j) S[i][j] = (f32x4){0.f, 0.f, 0.f, 0.f};
  bf16x8 kf[4];
#pragma unroll
  for (int j = 0; j < 4; ++j)
    kf[j] = *(const bf16x8*)&wb[(j * 16 + l16) * 40 + quad * 8];
#pragma unroll
  for (int i = 0; i < 4; ++i)
#pragma unroll
    for (int j = 0; j < 4; ++j)
      S[i][j] = __builtin_amdgcn_mfma_f32_16x16x32_bf16(qf[i], kf[j], S[i][j], 0, 0, 0);

  // ---- scale + rel-pos bias + shift mask (padding cols get -1e30 via maskPad)
  const float* mrow = maskPad + (size_t)(win_g & 255) * 4096;
  const float* brow = biasPad + (size_t)h * 4096;
#pragma unroll
  for (int i = 0; i < 4; ++i)
#pragma unroll
    for (int j = 0; j < 4; ++j)
#pragma unroll
      for (int r = 0; r < 4; ++r) {
        int q = i * 16 + quad * 4 + r;
        int k = j * 16 + l16;
        S[i][j][r] = fmaf(S[i][j][r], SCALE, brow[q * 64 + k] + mrow[q * 64 + k]);
      }

  // ---- row softmax in registers. Row q lives in one quad: 4 in-lane cols (j) x 16 lanes.
  float inv[4][4];
#pragma unroll
  for (int i = 0; i < 4; ++i)
#pragma unroll
    for (int r = 0; r < 4; ++r) {
      float mx = fmaxf(fmaxf(S[i][0][r], S[i][1][r]), fmaxf(S[i][2][r], S[i][3][r]));
      mx = fmaxf(mx, __shfl_xor(mx, 1, 64));
      mx = fmaxf(mx, __shfl_xor(mx, 2, 64));
      mx = fmaxf(mx, __shfl_xor(mx, 4, 64));
      mx = fmaxf(mx, __shfl_xor(mx, 8, 64));
      float sum = 0.f;
#pragma unroll
      for (int j = 0; j < 4; ++j) {
        float e = __expf(S[i][j][r] - mx);
        S[i][j][r] = e;
        sum += e;
      }
      sum += __shfl_xor(sum, 1, 64);
      sum += __shfl_xor(sum, 2, 64);
      sum += __shfl_xor(sum, 4, 64);
      sum += __shfl_xor(sum, 8, 64);
      inv[i][r] = 1.f / sum;   // deferred normalization, applied in epilogue
    }

  // ---- P (unnormalized, bf16) -> LDS, overlaying Ks (kf already consumed; in-wave DS order)
#pragma unroll
  for (int i = 0; i < 4; ++i)
#pragma unroll
    for (int j = 0; j < 4; ++j)
#pragma unroll
      for (int r = 0; r < 4; ++r) {
        int q = i * 16 + quad * 4 + r;
        int k = j * 16 + l16;
        *(__hip_bfloat16*)&wb[q * 72 + k] = __float2bfloat16(S[i][j][r]);
      }

  // ---- O = P V  (16 MFMAs). B operand = Vt[d][tok].
  f32x4 Oacc[4][2];
#pragma unroll
  for (int i = 0; i < 4; ++i) {
    Oacc[i][0] = (f32x4){0.f, 0.f, 0.f, 0.f};
    Oacc[i][1] = (f32x4){0.f, 0.f, 0.f, 0.f};
  }
  bf16x8 vf[2][2];
#pragma unroll
  for (int ks = 0; ks < 2; ++ks)
#pragma unroll
    for (int jp = 0; jp < 2; ++jp)
      vf[ks][jp] = *(const bf16x8*)&Vt[(jp * 16 + l16) * 64 + ks * 32 + quad * 8];
#pragma unroll
  for (int i = 0; i < 4; ++i)
#pragma unroll
    for (int ks = 0; ks < 2; ++ks) {
      bf16x8 pf = *(const bf16x8*)&wb[(i * 16 + l16) * 72 + ks * 32 + quad * 8];
#pragma unroll
      for (int jp = 0; jp < 2; ++jp)
        Oacc[i][jp] = __builtin_amdgcn_mfma_f32_16x16x32_bf16(pf, vf[ks][jp], Oacc[i][jp], 0, 0, 0);
    }

  // ---- epilogue: normalize rows, store bf16 (only q<49)
  __hip_bfloat16* ob = O + ((size_t)win_g * NTOK) * CC + h * HD;
#pragma unroll
  for (int i = 0; i < 4; ++i)
#pragma unroll
    for (int r = 0; r < 4; ++r) {
      int q = i * 16 + quad * 4 + r;
      if (q < NTOK) {
        float s = inv[i][r];
#pragma unroll
        for (int jp = 0; jp < 2; ++jp)
          ob[(size_t)q * CC + jp * 16 + l16] = __float2bfloat16(Oacc[i][jp][r] * s);
      }
    }
}

// ---------------------------------------------------------------- launch
extern "C" void kernel_launch(void* const* d_in, const int* in_sizes, int n_in,
                              void* d_out, int out_size, void* d_ws, size_t ws_size,
                              hipStream_t stream) {
  const float* x        = (const float*)d_in[0];
  const float* attnmask = (const float*)d_in[3];
  const float* ln1_g    = (const float*)d_in[4];
  const float* ln1_b    = (const float*)d_in[5];
  const float* qkv_w    = (const float*)d_in[6];
  const float* qkv_b    = (const float*)d_in[7];
  const float* table    = (const float*)d_in[8];
  const float* proj_w   = (const float*)d_in[9];
  const float* proj_b   = (const float*)d_in[10];
  const float* ln2_g    = (const float*)d_in[11];
  const float* ln2_b    = (const float*)d_in[12];
  const float* fc1_w    = (const float*)d_in[13];
  const float* fc1_b    = (const float*)d_in[14];
  const float* fc2_w    = (const float*)d_in[15];
  const float* fc2_b    = (const float*)d_in[16];
  float* out = (float*)d_out;   // x1 lives here

  // ws layout (bf16): bufA 25.69M elems | bufB 38.54M elems | weights | attn tables
  __hip_bfloat16* bufA = (__hip_bfloat16*)d_ws;                 // xw -> o -> f
  __hip_bfloat16* bufB = bufA + (size_t)NROWS * CC;             // qkv/h1 chunks
  __hip_bfloat16* wq   = bufB + (size_t)(NROWS / 2) * 384;
  __hip_bfloat16* wp   = wq + 384 * 128;
  __hip_bfloat16* w1   = wp + 128 * 128;
  __hip_bfloat16* w2   = w1 + 512 * 128;
  float* biasPad = (float*)(w2 + 128 * 512);                    // [4][64][64]
  float* maskPad = biasPad + 4 * 4096;                          // [256][64][64]

  // 0. cast weights to bf16 + build padded attn tables
  castw_kernel<<<(384 * 128 + 255) / 256, 256, 0, stream>>>(qkv_w, wq, 384 * 128);
  castw_kernel<<<(128 * 128 + 255) / 256, 256, 0, stream>>>(proj_w, wp, 128 * 128);
  castw_kernel<<<(512 * 128 + 255) / 256, 256, 0, stream>>>(fc1_w, w1, 512 * 128);
  castw_kernel<<<(128 * 512 + 255) / 256, 256, 0, stream>>>(fc2_w, w2, 128 * 512);
  prep_bias<<<64, 256, 0, stream>>>(table, biasPad);
  prep_mask<<<4096, 256, 0, stream>>>(attnmask, maskPad);

  // 1. LN1 + roll + window partition: x -> bufA (bf16)
  ln_kernel<true><<<NROWS / 4, 256, 0, stream>>>(x, ln1_g, ln1_b, bufA);

  // 2+3. qkv GEMM + attention, 2 chunks of M/2 rows (2048 windows each)
  for (int c = 0; c < 2; ++c) {
    const int MC = NROWS / 2;           // 100352
    const ushort_t* Ain = (const ushort_t*)(bufA + (size_t)c * MC * CC);
    dim3 g(MC / 128, 384 / 128);
    gemm_bf16<EPI_BIAS><<<g, 256, 0, stream>>>(Ain, (const ushort_t*)wq, qkv_b,
                                               nullptr, bufB, 384, 128);
    attn_mfma<<<2048, 256, 0, stream>>>((const ushort_t*)bufB, maskPad, biasPad,
                                        bufA, c * 2048);
  }

  // 4. proj GEMM + reverse/roll/residual scatter -> d_out (fp32 x1)
  {
    dim3 g(NROWS / 128, 1);
    gemm_bf16<EPI_PROJ><<<g, 256, 0, stream>>>((const ushort_t*)bufA, (const ushort_t*)wp,
                                               proj_b, x, out, 128, 128);
  }
  // 5. LN2: d_out -> bufA (bf16 f)
  ln_kernel<false><<<NROWS / 4, 256, 0, stream>>>(out, ln2_g, ln2_b, bufA);

  // 6+7. fc1+GELU, fc2+residual, 4 chunks of M/4 rows
  for (int c = 0; c < 4; ++c) {
    const int MC = NROWS / 4;           // 50176
    const ushort_t* Ain = (const ushort_t*)(bufA + (size_t)c * MC * CC);
    float* Oc = out + (size_t)c * MC * CC;
    dim3 g1(MC / 128, 512 / 128);
    gemm_bf16<EPI_GELU><<<g1, 256, 0, stream>>>(Ain, (const ushort_t*)w1, fc1_b,
                                                nullptr, bufB, 512, 128);
    dim3 g2(MC / 128, 1);
    gemm_bf16<EPI_RES><<<g2, 256, 0, stream>>>((const ushort_t*)bufB, (const ushort_t*)w2,
                                               fc2_b, Oc, Oc, 128, 512);
  }
}

// Round 3
// 612.623 us; speedup vs baseline: 1.5854x; 1.0651x over previous
//
#include <hip/hip_runtime.h>
#include <hip/hip_bf16.h>
#include <math.h>

#define B_IMG 16
#define HH 112
#define WW_ 112
#define CC 128
#define LL (HH*WW_)            // 12544
#define BWIN 4096
#define NTOK 49
#define NROWS (BWIN*NTOK)      // 200704
#define HD 32
#define SCALE 0.1767766952966369f   // 1/sqrt(32)
#define SHIFT_ 3

typedef short bf16x8 __attribute__((ext_vector_type(8)));
typedef float f32x4 __attribute__((ext_vector_type(4)));
typedef unsigned short ushort_t;

// ---------------------------------------------------------------- helpers
__device__ __forceinline__ float wave_sum(float v) {
#pragma unroll
  for (int off = 32; off >= 1; off >>= 1) v += __shfl_xor(v, off, 64);
  return v;
}

__global__ __launch_bounds__(256) void castw_kernel(const float* __restrict__ w,
                                                    __hip_bfloat16* __restrict__ o, int n) {
  int i = blockIdx.x * 256 + threadIdx.x;
  if (i < n) o[i] = __float2bfloat16(w[i]);
}

// ---------------------------------------------------------------- attention prep tables
__global__ __launch_bounds__(256) void prep_bias(const float* __restrict__ table,
                                                 float* __restrict__ biasPad) {
  int idx = blockIdx.x * 256 + threadIdx.x;      // 4*64*64 = 16384
  int h = idx >> 12, q = (idx >> 6) & 63, k = idx & 63;
  float v = 0.f;
  if (q < NTOK && k < NTOK) {
    int yi = q / 7, xi = q % 7, yj = k / 7, xj = k % 7;
    v = table[((yi - yj + 6) * 13 + (xi - xj + 6)) * 4 + h];
  }
  biasPad[idx] = v;
}

__global__ __launch_bounds__(256) void prep_mask(const float* __restrict__ mask,
                                                 float* __restrict__ maskPad) {
  int idx = blockIdx.x * 256 + threadIdx.x;      // 256*64*64 = 1048576
  int pat = idx >> 12, q = (idx >> 6) & 63, k = idx & 63;
  float v = -1e30f;
  if (q < NTOK && k < NTOK) v = mask[pat * (NTOK * NTOK) + q * NTOK + k];
  maskPad[idx] = v;
}

// ---------------------------------------------------------------- LayerNorm (fp32 in, bf16 out)
template<bool GATHER>
__global__ __launch_bounds__(256) void ln_kernel(
    const float* __restrict__ X, const float* __restrict__ g,
    const float* __restrict__ b, __hip_bfloat16* __restrict__ Y)
{
  int wid  = threadIdx.x >> 6;
  int lane = threadIdx.x & 63;
  int r = blockIdx.x * 4 + wid;
  size_t src;
  if (GATHER) {
    int win = r / NTOK, n = r % NTOK;
    int bi = win >> 8, wi = win & 255;
    int wh = wi >> 4, wwi = wi & 15;
    int ii = n / 7, jj = n % 7;
    int hp = wh * 7 + ii, wp = wwi * 7 + jj;
    int sh = (hp + SHIFT_) % HH, sw = (wp + SHIFT_) % WW_;   // roll(-3) gather
    src = ((size_t)bi * LL + (size_t)sh * WW_ + sw) * CC;
  } else {
    src = (size_t)r * CC;
  }
  float v0 = X[src + lane];
  float v1 = X[src + 64 + lane];
  float mean = wave_sum(v0 + v1) * (1.f / CC);
  float d0 = v0 - mean, d1 = v1 - mean;
  float var = wave_sum(d0 * d0 + d1 * d1) * (1.f / CC);
  float rstd = rsqrtf(var + 1e-5f);
  size_t dst = (size_t)r * CC;
  Y[dst + lane]      = __float2bfloat16(d0 * rstd * g[lane]      + b[lane]);
  Y[dst + 64 + lane] = __float2bfloat16(d1 * rstd * g[lane + 64] + b[lane + 64]);
}

// ---------------------------------------------------------------- bf16 MFMA GEMM
// C[m][n] = sum_k A[m][k]*W[n][k] + bias[n]  (+ epilogue). A,W bf16; acc fp32.
// 128x128 tile, 256 thr = 4 waves (2x2), each wave 64x64 via 4x4 of 16x16x32.
// NB>1 (requires K==128): A panel staged once, loop over NB B-panels in-block.
// EPI_PROJ + LNF: fuses LayerNorm2; ln_out written at LINEAR token offsets
// (same scatter as x1) into a buffer that does NOT alias A.
enum { EPI_BIAS = 0, EPI_GELU = 1, EPI_RES = 2, EPI_PROJ = 3 };
#define LDSW 136   // 128 + 8 pad: keeps 16B alignment, breaks bank-phase

#define STAGE_A(KB)                                                              \
  _Pragma("unroll")                                                              \
  for (int p = 0; p < 8; ++p) {                                                  \
    int lin = p * 256 + t;                                                       \
    int row = lin >> 4;                                                          \
    int col = (lin & 15) * 8;                                                    \
    *(uint4*)&As[row * LDSW + col] =                                             \
        *(const uint4*)(A + (size_t)(m0 + row) * K + (KB) + col);                \
  }

#define STAGE_B(NOFF, KB)                                                        \
  _Pragma("unroll")                                                              \
  for (int p = 0; p < 8; ++p) {                                                  \
    int lin = p * 256 + t;                                                       \
    int row = lin >> 4;                                                          \
    int col = (lin & 15) * 8;                                                    \
    *(uint4*)&Bs[row * LDSW + col] =                                             \
        *(const uint4*)(W + (size_t)((NOFF) + row) * K + (KB) + col);            \
  }

#define MFMA_BLOCK                                                               \
  _Pragma("unroll")                                                              \
  for (int ks = 0; ks < 4; ++ks) {                                               \
    int k0 = ks * 32 + quad * 8;                                                 \
    bf16x8 af[4], bf[4];                                                         \
    _Pragma("unroll")                                                            \
    for (int i = 0; i < 4; ++i)                                                  \
      af[i] = *(const bf16x8*)&As[(wr + i * 16 + l16) * LDSW + k0];              \
    _Pragma("unroll")                                                            \
    for (int j = 0; j < 4; ++j)                                                  \
      bf[j] = *(const bf16x8*)&Bs[(wc + j * 16 + l16) * LDSW + k0];              \
    _Pragma("unroll")                                                            \
    for (int i = 0; i < 4; ++i)                                                  \
      _Pragma("unroll")                                                          \
      for (int j = 0; j < 4; ++j)                                                \
        acc[i][j] = __builtin_amdgcn_mfma_f32_16x16x32_bf16(af[i], bf[j],        \
                                                            acc[i][j], 0, 0, 0); \
  }

template<int EPI, int NB, bool LNF>
__global__ __launch_bounds__(256, 2) void gemm_bf16(
    const ushort_t* __restrict__ A, const ushort_t* __restrict__ W,
    const float* __restrict__ bias, const float* __restrict__ aux,
    void* __restrict__ outp, const float* __restrict__ g2,
    const float* __restrict__ b2, __hip_bfloat16* __restrict__ ln_out,
    int N, int K)
{
  __shared__ ushort_t As[128 * LDSW];
  __shared__ ushort_t Bs[128 * LDSW];
  int t = threadIdx.x;
  int lane = t & 63;
  int quad = lane >> 4;
  int l16  = lane & 15;
  int wr = (t >> 7) * 64;        // wave row offset in tile
  int wc = ((t >> 6) & 1) * 64;  // wave col offset in tile
  int m0 = blockIdx.x * 128;

  f32x4 acc[4][4];

  for (int nb = 0; nb < NB; ++nb) {
    int n_off = (NB == 1) ? blockIdx.y * 128 : nb * 128;
#pragma unroll
    for (int i = 0; i < 4; ++i)
#pragma unroll
      for (int j = 0; j < 4; ++j) acc[i][j] = (f32x4){0.f, 0.f, 0.f, 0.f};

    if (NB == 1) {
      for (int kb = 0; kb < K; kb += 128) {
        if (kb) __syncthreads();
        STAGE_A(kb);
        STAGE_B(n_off, kb);
        __syncthreads();
        MFMA_BLOCK;
      }
    } else {           // K == 128: A resident across B panels
      if (nb == 0) { STAGE_A(0); STAGE_B(0, 0); }
      __syncthreads();
      MFMA_BLOCK;
      __syncthreads();
      if (nb + 1 < NB) { STAGE_B((nb + 1) * 128, 0); }
    }

    // ---------------- epilogue: C/D layout col=lane&15, row=quad*4+reg
    if (EPI == EPI_PROJ) {
      // pass 1: x1 = shortcut + (acc+bias); scatter fp32 at linear offsets
      float s[4][4], ss[4][4];
      unsigned rowB[4][4];
#pragma unroll
      for (int i = 0; i < 4; ++i) {
#pragma unroll
        for (int r = 0; r < 4; ++r) {
          s[i][r] = 0.f; ss[i][r] = 0.f;
          int m = m0 + wr + i * 16 + quad * 4 + r;
          int win = m / NTOK, nn = m % NTOK;
          int bi = win >> 8, wi = win & 255;
          int wh = wi >> 4, wwi = wi & 15;
          int ii = nn / 7, jj = nn % 7;
          int hp = wh * 7 + ii, wp = wwi * 7 + jj;
          int oh = (hp + SHIFT_) % HH, ow = (wp + SHIFT_) % WW_;
          unsigned base = ((unsigned)bi * LL + (unsigned)oh * WW_ + ow) * CC;
          rowB[i][r] = base;
#pragma unroll
          for (int j = 0; j < 4; ++j) {
            int n = wc + j * 16 + l16;
            float x1 = aux[base + n] + acc[i][j][r] + bias[n];
            ((float*)outp)[base + n] = x1;
            if (LNF) {
              acc[i][j][r] = x1;
              s[i][r] += x1;
              ss[i][r] = fmaf(x1, x1, ss[i][r]);
            }
          }
        }
      }
      if (LNF) {
        // reduce across the 16 lanes of each quad-row group
#pragma unroll
        for (int i = 0; i < 4; ++i)
#pragma unroll
          for (int r = 0; r < 4; ++r) {
#pragma unroll
            for (int off = 8; off >= 1; off >>= 1) {
              s[i][r]  += __shfl_xor(s[i][r],  off, 64);
              ss[i][r] += __shfl_xor(ss[i][r], off, 64);
            }
          }
        // cross-wave (col-half) combine via LDS
        float* red = (float*)As;              // [2][128][2] = 2 KB
        __syncthreads();                      // all waves done reading As
        if (l16 == 0) {
#pragma unroll
          for (int i = 0; i < 4; ++i)
#pragma unroll
            for (int r = 0; r < 4; ++r) {
              int ml = wr + i * 16 + quad * 4 + r;
              red[((wc >> 6) * 128 + ml) * 2 + 0] = s[i][r];
              red[((wc >> 6) * 128 + ml) * 2 + 1] = ss[i][r];
            }
        }
        __syncthreads();
#pragma unroll
        for (int i = 0; i < 4; ++i)
#pragma unroll
          for (int r = 0; r < 4; ++r) {
            int ml = wr + i * 16 + quad * 4 + r;
            float st  = red[ml * 2 + 0] + red[(128 + ml) * 2 + 0];
            float sst = red[ml * 2 + 1] + red[(128 + ml) * 2 + 1];
            float mean = st * (1.f / 128.f);
            float var  = sst * (1.f / 128.f) - mean * mean;
            s[i][r]  = mean;
            ss[i][r] = rsqrtf(var + 1e-5f);
          }
        // pass 2: LN2 -> bf16 ln_out at LINEAR token offsets (no alias with A)
#pragma unroll
        for (int i = 0; i < 4; ++i)
#pragma unroll
          for (int r = 0; r < 4; ++r) {
            unsigned base = rowB[i][r];
#pragma unroll
            for (int j = 0; j < 4; ++j) {
              int n = wc + j * 16 + l16;
              float ln = (acc[i][j][r] - s[i][r]) * ss[i][r] * g2[n] + b2[n];
              ln_out[(size_t)base + n] = __float2bfloat16(ln);
            }
          }
      }
    } else {
#pragma unroll
      for (int i = 0; i < 4; ++i) {
#pragma unroll
        for (int j = 0; j < 4; ++j) {
          int n = n_off + wc + j * 16 + l16;
          float bn = bias[n];
#pragma unroll
          for (int reg = 0; reg < 4; ++reg) {
            int m = m0 + wr + i * 16 + quad * 4 + reg;
            float v = acc[i][j][reg] + bn;
            if (EPI == EPI_BIAS) {
              ((__hip_bfloat16*)outp)[(size_t)m * N + n] = __float2bfloat16(v);
            } else if (EPI == EPI_GELU) {
              v = 0.5f * v * (1.f + erff(v * 0.70710678118654752f));
              ((__hip_bfloat16*)outp)[(size_t)m * N + n] = __float2bfloat16(v);
            } else { // EPI_RES: in-place residual (aux aliases outp)
              ((float*)outp)[(size_t)m * N + n] = v + aux[(size_t)m * N + n];
            }
          }
        }
      }
    }
  }
}

// ---------------------------------------------------------------- MFMA attention
// 1 block = 1 window; 4 waves = 4 heads; tokens padded 49->64.
#define WLDS 6656

__global__ __launch_bounds__(256) void attn_mfma(
    const ushort_t* __restrict__ qkv, const float* __restrict__ maskPad,
    const float* __restrict__ biasPad, __hip_bfloat16* __restrict__ O, int win_off)
{
  __shared__ ushort_t lds[4 * WLDS];
  const int win_l = blockIdx.x;
  const int win_g = win_off + win_l;
  const int h    = threadIdx.x >> 6;
  const int lane = threadIdx.x & 63;
  const int quad = lane >> 4;
  const int l16  = lane & 15;
  ushort_t* wb = lds + h * WLDS;     // Ks, later P
  ushort_t* Vt = wb + 4608;

  // ---- stage K (zero-padded rows to 64) and V^T for this head (wave-private)
  {
    const int tok = lane;
    uint4 z = make_uint4(0u, 0u, 0u, 0u);
    uint4 k0 = z, k1 = z, k2 = z, k3 = z;
    union { uint4 v4[4]; ushort_t u[32]; } vv;
    vv.v4[0] = z; vv.v4[1] = z; vv.v4[2] = z; vv.v4[3] = z;
    if (tok < NTOK) {
      const ushort_t* src = qkv + ((size_t)win_l * NTOK + tok) * 384 + h * HD;
      k0 = *(const uint4*)(src + 128); k1 = *(const uint4*)(src + 136);
      k2 = *(const uint4*)(src + 144); k3 = *(const uint4*)(src + 152);
      vv.v4[0] = *(const uint4*)(src + 256); vv.v4[1] = *(const uint4*)(src + 264);
      vv.v4[2] = *(const uint4*)(src + 272); vv.v4[3] = *(const uint4*)(src + 280);
    }
    *(uint4*)&wb[tok * 40 +  0] = k0;
    *(uint4*)&wb[tok * 40 +  8] = k1;
    *(uint4*)&wb[tok * 40 + 16] = k2;
    *(uint4*)&wb[tok * 40 + 24] = k3;
#pragma unroll
    for (int d = 0; d < 32; ++d) Vt[d * 64 + tok] = vv.u[d];
  }

  // ---- Q fragments straight from global (rows >=49 read garbage; rows unused)
  bf16x8 qf[4];
  {
    const ushort_t* qb = qkv + (size_t)win_l * NTOK * 384 + h * HD + quad * 8;
#pragma unroll
    for (int i = 0; i < 4; ++i)
      qf[i] = *(const bf16x8*)(qb + (size_t)(i * 16 + l16) * 384);
  }

  // ---- S = Q K^T  (16 MFMAs)
  f32x4 S[4][4];
#pragma unroll
  for (int i = 0; i < 4; ++i)
#pragma unroll
    for (int j = 0; j < 4; ++j) S[i][j] = (f32x4){0.f, 0.f, 0.f, 0.f};
  bf16x8 kf[4];
#pragma unroll
  for (int j = 0; j < 4; ++j)
    kf[j] = *(const bf16x8*)&wb[(j * 16 + l16) * 40 + quad * 8];
#pragma unroll
  for (int i = 0; i < 4; ++i)
#pragma unroll
    for (int j = 0; j < 4; ++j)
      S[i][j] = __builtin_amdgcn_mfma_f32_16x16x32_bf16(qf[i], kf[j], S[i][j], 0, 0, 0);

  // ---- scale + rel-pos bias + shift mask (padding cols get -1e30 via maskPad)
  const float* mrow = maskPad + (size_t)(win_g & 255) * 4096;
  const float* brow = biasPad + (size_t)h * 4096;
#pragma unroll
  for (int i = 0; i < 4; ++i)
#pragma unroll
    for (int j = 0; j < 4; ++j)
#pragma unroll
      for (int r = 0; r < 4; ++r) {
        int q = i * 16 + quad * 4 + r;
        int k = j * 16 + l16;
        S[i][j][r] = fmaf(S[i][j][r], SCALE, brow[q * 64 + k] + mrow[q * 64 + k]);
      }

  // ---- row softmax in registers
  float inv[4][4];
#pragma unroll
  for (int i = 0; i < 4; ++i)
#pragma unroll
    for (int r = 0; r < 4; ++r) {
      float mx = fmaxf(fmaxf(S[i][0][r], S[i][1][r]), fmaxf(S[i][2][r], S[i][3][r]));
      mx = fmaxf(mx, __shfl_xor(mx, 1, 64));
      mx = fmaxf(mx, __shfl_xor(mx, 2, 64));
      mx = fmaxf(mx, __shfl_xor(mx, 4, 64));
      mx = fmaxf(mx, __shfl_xor(mx, 8, 64));
      float sum = 0.f;
#pragma unroll
      for (int j = 0; j < 4; ++j) {
        float e = __expf(S[i][j][r] - mx);
        S[i][j][r] = e;
        sum += e;
      }
      sum += __shfl_xor(sum, 1, 64);
      sum += __shfl_xor(sum, 2, 64);
      sum += __shfl_xor(sum, 4, 64);
      sum += __shfl_xor(sum, 8, 64);
      inv[i][r] = 1.f / sum;   // deferred normalization
    }

  // ---- P (unnormalized, bf16) -> LDS, overlaying Ks
#pragma unroll
  for (int i = 0; i < 4; ++i)
#pragma unroll
    for (int j = 0; j < 4; ++j)
#pragma unroll
      for (int r = 0; r < 4; ++r) {
        int q = i * 16 + quad * 4 + r;
        int k = j * 16 + l16;
        *(__hip_bfloat16*)&wb[q * 72 + k] = __float2bfloat16(S[i][j][r]);
      }

  // ---- O = P V  (16 MFMAs)
  f32x4 Oacc[4][2];
#pragma unroll
  for (int i = 0; i < 4; ++i) {
    Oacc[i][0] = (f32x4){0.f, 0.f, 0.f, 0.f};
    Oacc[i][1] = (f32x4){0.f, 0.f, 0.f, 0.f};
  }
  bf16x8 vf[2][2];
#pragma unroll
  for (int ks = 0; ks < 2; ++ks)
#pragma unroll
    for (int jp = 0; jp < 2; ++jp)
      vf[ks][jp] = *(const bf16x8*)&Vt[(jp * 16 + l16) * 64 + ks * 32 + quad * 8];
#pragma unroll
  for (int i = 0; i < 4; ++i)
#pragma unroll
    for (int ks = 0; ks < 2; ++ks) {
      bf16x8 pf = *(const bf16x8*)&wb[(i * 16 + l16) * 72 + ks * 32 + quad * 8];
#pragma unroll
      for (int jp = 0; jp < 2; ++jp)
        Oacc[i][jp] = __builtin_amdgcn_mfma_f32_16x16x32_bf16(pf, vf[ks][jp], Oacc[i][jp], 0, 0, 0);
    }

  // ---- epilogue: normalize rows, store bf16 (only q<49)
  __hip_bfloat16* ob = O + ((size_t)win_g * NTOK) * CC + h * HD;
#pragma unroll
  for (int i = 0; i < 4; ++i)
#pragma unroll
    for (int r = 0; r < 4; ++r) {
      int q = i * 16 + quad * 4 + r;
      if (q < NTOK) {
        float sc = inv[i][r];
#pragma unroll
        for (int jp = 0; jp < 2; ++jp)
          ob[(size_t)q * CC + jp * 16 + l16] = __float2bfloat16(Oacc[i][jp][r] * sc);
      }
    }
}

// ---------------------------------------------------------------- launch
extern "C" void kernel_launch(void* const* d_in, const int* in_sizes, int n_in,
                              void* d_out, int out_size, void* d_ws, size_t ws_size,
                              hipStream_t stream) {
  const float* x        = (const float*)d_in[0];
  const float* attnmask = (const float*)d_in[3];
  const float* ln1_g    = (const float*)d_in[4];
  const float* ln1_b    = (const float*)d_in[5];
  const float* qkv_w    = (const float*)d_in[6];
  const float* qkv_b    = (const float*)d_in[7];
  const float* table    = (const float*)d_in[8];
  const float* proj_w   = (const float*)d_in[9];
  const float* proj_b   = (const float*)d_in[10];
  const float* ln2_g    = (const float*)d_in[11];
  const float* ln2_b    = (const float*)d_in[12];
  const float* fc1_w    = (const float*)d_in[13];
  const float* fc1_b    = (const float*)d_in[14];
  const float* fc2_w    = (const float*)d_in[15];
  const float* fc2_b    = (const float*)d_in[16];
  float* out = (float*)d_out;   // x1 lives here

  const size_t bufA_elems = (size_t)NROWS * CC;            // 25.7M
  const size_t bufB_full  = (size_t)NROWS * 512;           // 102.8M
  const size_t bufB_chunk = (size_t)(NROWS / 2) * 384;     // 38.5M
  const size_t bufC_elems = (size_t)NROWS * CC;            // 25.7M (LN2 out)
  const size_t w_elems    = 384*128 + 128*128 + 512*128 + 128*512;
  const size_t tbl_floats = 4 * 4096 + 256 * 4096;
  const size_t need_full  =
      (bufA_elems + bufB_full + bufC_elems + w_elems) * 2 + tbl_floats * 4;
  const bool full = ws_size >= need_full;

  __hip_bfloat16* bufA = (__hip_bfloat16*)d_ws;            // xw -> o  (chunk: + LN2 f)
  __hip_bfloat16* bufB = bufA + bufA_elems;                // qkv / h1
  __hip_bfloat16* bufC;                                    // LN2 out (full path)
  __hip_bfloat16* wq;
  if (full) {
    bufC = bufB + bufB_full;
    wq   = bufC + bufC_elems;
  } else {
    bufC = nullptr;
    wq   = bufB + bufB_chunk;
  }
  __hip_bfloat16* wp   = wq + 384 * 128;
  __hip_bfloat16* w1   = wp + 128 * 128;
  __hip_bfloat16* w2   = w1 + 512 * 128;
  float* biasPad = (float*)(w2 + 128 * 512);               // [4][64][64]
  float* maskPad = biasPad + 4 * 4096;                     // [256][64][64]

  // 0. cast weights to bf16 + build padded attn tables
  castw_kernel<<<(384 * 128 + 255) / 256, 256, 0, stream>>>(qkv_w, wq, 384 * 128);
  castw_kernel<<<(128 * 128 + 255) / 256, 256, 0, stream>>>(proj_w, wp, 128 * 128);
  castw_kernel<<<(512 * 128 + 255) / 256, 256, 0, stream>>>(fc1_w, w1, 512 * 128);
  castw_kernel<<<(128 * 512 + 255) / 256, 256, 0, stream>>>(fc2_w, w2, 128 * 512);
  prep_bias<<<64, 256, 0, stream>>>(table, biasPad);
  prep_mask<<<4096, 256, 0, stream>>>(attnmask, maskPad);

  // 1. LN1 + roll + window partition: x -> bufA (bf16)
  ln_kernel<true><<<NROWS / 4, 256, 0, stream>>>(x, ln1_g, ln1_b, bufA);

  if (full) {
    // 2. qkv GEMM (A resident over 3 B-panels): bufA -> bufB
    dim3 g(NROWS / 128, 1);
    gemm_bf16<EPI_BIAS, 3, false><<<g, 256, 0, stream>>>(
        (const ushort_t*)bufA, (const ushort_t*)wq, qkv_b, nullptr, bufB,
        nullptr, nullptr, nullptr, 384, 128);
    // 3. attention: bufB -> bufA (o)
    attn_mfma<<<BWIN, 256, 0, stream>>>((const ushort_t*)bufB, maskPad, biasPad,
                                        bufA, 0);
    // 4. proj GEMM + residual scatter -> out (x1) + fused LN2 -> bufC (linear)
    gemm_bf16<EPI_PROJ, 1, true><<<g, 256, 0, stream>>>(
        (const ushort_t*)bufA, (const ushort_t*)wp, proj_b, x, out,
        ln2_g, ln2_b, bufC, 128, 128);
    // 5. fc1 + GELU (A resident over 4 B-panels): bufC -> bufB
    gemm_bf16<EPI_GELU, 4, false><<<g, 256, 0, stream>>>(
        (const ushort_t*)bufC, (const ushort_t*)w1, fc1_b, nullptr, bufB,
        nullptr, nullptr, nullptr, 512, 128);
    // 6. fc2 + residual (in-place on out): bufB -> out
    gemm_bf16<EPI_RES, 1, false><<<g, 256, 0, stream>>>(
        (const ushort_t*)bufB, (const ushort_t*)w2, fc2_b, out, out,
        nullptr, nullptr, nullptr, 128, 512);
  } else {
    // fallback: round-1-verified chunked structure, separate LN2
    for (int c = 0; c < 2; ++c) {
      const int MC = NROWS / 2;
      const ushort_t* Ain = (const ushort_t*)(bufA + (size_t)c * MC * CC);
      dim3 g(MC / 128, 1);
      gemm_bf16<EPI_BIAS, 3, false><<<g, 256, 0, stream>>>(
          Ain, (const ushort_t*)wq, qkv_b, nullptr, bufB,
          nullptr, nullptr, nullptr, 384, 128);
      attn_mfma<<<2048, 256, 0, stream>>>((const ushort_t*)bufB, maskPad, biasPad,
                                          bufA, c * 2048);
    }
    {
      dim3 g(NROWS / 128, 1);
      gemm_bf16<EPI_PROJ, 1, false><<<g, 256, 0, stream>>>(
          (const ushort_t*)bufA, (const ushort_t*)wp, proj_b, x, out,
          nullptr, nullptr, nullptr, 128, 128);
    }
    ln_kernel<false><<<NROWS / 4, 256, 0, stream>>>(out, ln2_g, ln2_b, bufA);
    for (int c = 0; c < 4; ++c) {
      const int MC = NROWS / 4;
      const ushort_t* Ain = (const ushort_t*)(bufA + (size_t)c * MC * CC);
      float* Oc = out + (size_t)c * MC * CC;
      dim3 g1(MC / 128, 1);
      gemm_bf16<EPI_GELU, 4, false><<<g1, 256, 0, stream>>>(
          Ain, (const ushort_t*)w1, fc1_b, nullptr, bufB,
          nullptr, nullptr, nullptr, 512, 128);
      dim3 g2(MC / 128, 1);
      gemm_bf16<EPI_RES, 1, false><<<g2, 256, 0, stream>>>(
          (const ushort_t*)bufB, (const ushort_t*)w2, fc2_b, Oc, Oc,
          nullptr, nullptr, nullptr, 128, 512);
    }
  }
}